// Round 5
// baseline (599.718 us; speedup 1.0000x reference)
//
#include <hip/hip_runtime.h>
#include <hip/hip_bf16.h>

// ---------------- problem constants ----------------
#define B_SZ   8192
#define XD     362
#define NEXP   3
#define NTILES 70          // 128-row tile capacity (segments 256-aligned)
#define MP     (NTILES*128)

typedef __bf16 bf16x8 __attribute__((ext_vector_type(8)));
typedef float  f32x4  __attribute__((ext_vector_type(4)));
typedef float  f32x16 __attribute__((ext_vector_type(16)));

__device__ __forceinline__ unsigned short f2bf(float f) {
    unsigned u = __float_as_uint(f);
    u += 0x7fffu + ((u >> 16) & 1u);
    return (unsigned short)(u >> 16);
}

// hdr: [0..2]=counts, [6..8]=seg_start_row, [12]=total 128-tiles,
// [16]=float accumulator, [32..101]=128-tile -> expert (-1 = inactive)
__global__ __launch_bounds__(1024) void k_route(const int* __restrict__ a,
                                                int* __restrict__ hdr,
                                                int* __restrict__ row_of) {
    __shared__ int sc[3][1024];
    int tid = threadIdx.x;
    int ev[8];
    int c0 = 0, c1 = 0, c2 = 0;
#pragma unroll
    for (int j = 0; j < 8; ++j) {
        int e = a[tid * 8 + j];
        ev[j] = e;
        c0 += (e == 0); c1 += (e == 1); c2 += (e == 2);
    }
    sc[0][tid] = c0; sc[1][tid] = c1; sc[2][tid] = c2;
    __syncthreads();
    for (int off = 1; off < 1024; off <<= 1) {
        int v0 = (tid >= off) ? sc[0][tid - off] : 0;
        int v1 = (tid >= off) ? sc[1][tid - off] : 0;
        int v2 = (tid >= off) ? sc[2][tid - off] : 0;
        __syncthreads();
        sc[0][tid] += v0; sc[1][tid] += v1; sc[2][tid] += v2;
        __syncthreads();
    }
    int tot0 = sc[0][1023], tot1 = sc[1][1023], tot2 = sc[2][1023];
    int t0 = ((tot0 + 255) >> 8) << 1;
    int t1 = ((tot1 + 255) >> 8) << 1;
    int t2 = ((tot2 + 255) >> 8) << 1;
    int seg0 = 0, seg1 = t0 * 128, seg2 = (t0 + t1) * 128;
    int nt = t0 + t1 + t2;
    int b0 = seg0 + sc[0][tid] - c0;
    int b1 = seg1 + sc[1][tid] - c1;
    int b2 = seg2 + sc[2][tid] - c2;
#pragma unroll
    for (int j = 0; j < 8; ++j) {
        int e = ev[j];
        int pos = (e == 0) ? b0++ : (e == 1) ? b1++ : b2++;
        row_of[pos] = tid * 8 + j;
    }
    if (tid == 0) {
        hdr[0] = tot0; hdr[1] = tot1; hdr[2] = tot2;
        hdr[6] = seg0; hdr[7] = seg1; hdr[8] = seg2;
        hdr[12] = nt;
        hdr[16] = 0;
    }
    if (tid < NTILES)
        hdr[32 + tid] = (tid < t0) ? 0 : (tid < t0 + t1) ? 1 : (tid < nt) ? 2 : -1;
    for (int r = tid; r < MP; r += 1024) {
        int pad;
        if (r < seg1)           pad = (r - seg0) >= tot0;
        else if (r < seg2)      pad = (r - seg1) >= tot1;
        else if (r < nt * 128)  pad = (r - seg2) >= tot2;
        else                    pad = 1;
        if (pad) row_of[r] = -1;
    }
}

__global__ void k_gather(const float* __restrict__ x, const int* __restrict__ row_of,
                         unsigned short* __restrict__ xg) {
    int r = blockIdx.x;
    int c = threadIdx.x;
    int orig = row_of[r];
    float v = (orig >= 0 && c < XD) ? x[(size_t)orig * XD + c] : 0.f;
    xg[(size_t)r * 384 + c] = f2bf(v);
}

// ---------------- weight transpose+convert ----------------
__global__ void k_transpose(const float* __restrict__ W, unsigned short* __restrict__ Wt,
                            int K, int N, int Kp, int Np) {
    __shared__ float t[64][33];
    int e  = blockIdx.z;
    int kb = blockIdx.x * 64, nb = blockIdx.y * 32;
    const float* We = W + (size_t)e * K * N;
    unsigned short* Wte = Wt + (size_t)e * Np * Kp;
    int tx = threadIdx.x, ty = threadIdx.y;
#pragma unroll
    for (int j = 0; j < 8; ++j) {
        int k = kb + ty + j * 8, n = nb + tx;
        t[ty + j * 8][tx] = (k < K && n < N) ? We[(size_t)k * N + n] : 0.f;
    }
    __syncthreads();
#pragma unroll
    for (int j = 0; j < 4; ++j) {
        int n = ty + j * 8;
        unsigned int lo = f2bf(t[2 * tx][n]);
        unsigned int hi = f2bf(t[2 * tx + 1][n]);
        *(unsigned int*)&Wte[(size_t)(nb + n) * Kp + kb + 2 * tx] = lo | (hi << 16);
    }
}

// ---------------- small GEMM (16x16x32 frags), used for L0 and fused-MSE L4 ----------------
template <int TM, int TN, int WAVES, bool FINAL>
__global__ __launch_bounds__(WAVES * 64) void k_gemm16(
    const unsigned short* __restrict__ A, int lda,
    const unsigned short* __restrict__ Bt, int K, int Np,
    const float* __restrict__ bias, int nvalid,
    unsigned short* __restrict__ C, int ldc,
    const int* __restrict__ hdr,
    const float* __restrict__ nextv, const int* __restrict__ row_of,
    float* __restrict__ accum)
{
    __shared__ unsigned short As[2][TM * 64];
    __shared__ unsigned short Bs[2][TN * 64];
    __shared__ float red[WAVES];

    constexpr int WGN = TN / 64;
    constexpr int LA  = TM / (WAVES * 8);
    constexpr int LB  = TN / (WAVES * 8);

    int mt = blockIdx.y;
    int e  = hdr[32 + mt * (TM / 128)];
    if (e < 0) return;
    int row0 = mt * TM;
    int n0   = blockIdx.x * TN;

    int tid  = threadIdx.x;
    int wid  = tid >> 6, lane = tid & 63;
    int quad = lane >> 4, l15 = lane & 15;
    int sw   = l15 & 7;
    int wm = (wid / WGN) * 64, wn = (wid % WGN) * 64;

    const unsigned short* Ag = A  + (size_t)row0 * lda;
    const unsigned short* Bg = Bt + (size_t)e * Np * K + (size_t)n0 * K;
    const float* be = bias + (size_t)e * nvalid;

    int srow = lane >> 3;
    int scol = ((lane & 7) ^ srow) * 8;

    f32x4 acc[4][4];
#pragma unroll
    for (int i = 0; i < 4; ++i)
#pragma unroll
        for (int j = 0; j < 4; ++j)
            acc[i][j] = (f32x4){0.f, 0.f, 0.f, 0.f};

#define STAGE(K0, P)                                                              \
    {                                                                             \
        _Pragma("unroll")                                                         \
        for (int ii = 0; ii < LA; ++ii) {                                         \
            int rbase = wid * (TM / WAVES) + ii * 8;                              \
            const unsigned short* gp = Ag + (size_t)(rbase + srow) * lda + (K0) + scol; \
            __builtin_amdgcn_global_load_lds(                                     \
                (const __attribute__((address_space(1))) void*)gp,                \
                (__attribute__((address_space(3))) void*)(As[P] + rbase * 64), 16, 0, 0); \
        }                                                                         \
        _Pragma("unroll")                                                         \
        for (int ii = 0; ii < LB; ++ii) {                                         \
            int rbase = wid * (TN / WAVES) + ii * 8;                              \
            const unsigned short* gp = Bg + (size_t)(rbase + srow) * K + (K0) + scol;   \
            __builtin_amdgcn_global_load_lds(                                     \
                (const __attribute__((address_space(1))) void*)gp,                \
                (__attribute__((address_space(3))) void*)(Bs[P] + rbase * 64), 16, 0, 0); \
        }                                                                         \
    }

#define COMPUTE(P)                                                                \
    {                                                                             \
        _Pragma("unroll")                                                         \
        for (int kh = 0; kh < 2; ++kh) {                                          \
            bf16x8 af[4], bfr[4];                                                 \
            _Pragma("unroll")                                                     \
            for (int f = 0; f < 4; ++f) {                                         \
                int row = wm + f * 16 + l15;                                      \
                af[f] = *(const bf16x8*)(As[P] + row * 64 + (((kh * 4 + quad) ^ sw) << 3)); \
            }                                                                     \
            _Pragma("unroll")                                                     \
            for (int f = 0; f < 4; ++f) {                                         \
                int row = wn + f * 16 + l15;                                      \
                bfr[f] = *(const bf16x8*)(Bs[P] + row * 64 + (((kh * 4 + quad) ^ sw) << 3)); \
            }                                                                     \
            _Pragma("unroll")                                                     \
            for (int fm = 0; fm < 4; ++fm)                                        \
                _Pragma("unroll")                                                 \
                for (int fn = 0; fn < 4; ++fn)                                    \
                    acc[fm][fn] = __builtin_amdgcn_mfma_f32_16x16x32_bf16(        \
                        af[fm], bfr[fn], acc[fm][fn], 0, 0, 0);                   \
        }                                                                         \
    }

    STAGE(0, 0);
    __syncthreads();
    for (int k0 = 0; k0 < K; k0 += 128) {
        if (k0 + 64 < K) STAGE(k0 + 64, 1);
        COMPUTE(0);
        __syncthreads();
        if (k0 + 128 < K) STAGE(k0 + 128, 0);
        COMPUTE(1);
        __syncthreads();
    }
#undef STAGE
#undef COMPUTE

    if constexpr (!FINAL) {
#pragma unroll
        for (int fn = 0; fn < 4; ++fn) {
            int n = n0 + wn + fn * 16 + l15;
            float bv = be[n];
#pragma unroll
            for (int fm = 0; fm < 4; ++fm) {
#pragma unroll
                for (int i = 0; i < 4; ++i) {
                    int r = row0 + wm + fm * 16 + quad * 4 + i;
                    float v = acc[fm][fn][i] + bv;
                    v = v > 0.f ? v : 0.f;
                    C[(size_t)r * ldc + n] = f2bf(v);
                }
            }
        }
    } else {
        float local = 0.f;
#pragma unroll
        for (int fm = 0; fm < 4; ++fm) {
#pragma unroll
            for (int i = 0; i < 4; ++i) {
                int r = row0 + wm + fm * 16 + quad * 4 + i;
                int orig = row_of[r];
                if (orig >= 0) {
                    const float* nrow = nextv + (size_t)orig * XD;
#pragma unroll
                    for (int fn = 0; fn < 4; ++fn) {
                        int n = n0 + wn + fn * 16 + l15;
                        if (n < XD) {
                            float v = acc[fm][fn][i] + be[n];
                            float d = v - nrow[n];
                            local += d * d;
                        }
                    }
                }
            }
        }
        for (int off = 32; off > 0; off >>= 1)
            local += __shfl_down(local, off, 64);
        if (lane == 0) red[wid] = local;
        __syncthreads();
        if (tid == 0) {
            float s = 0.f;
#pragma unroll
            for (int w = 0; w < WAVES; ++w) s += red[w];
            atomicAdd(accum, s);
        }
    }
}

// ---------------- big GEMM: 256x256 block, 4 waves, 128x128/wave via 32x32x16 ----------------
// 1 wave/SIMD by design (256 acc regs). LDS bytes/FLOP halved vs 64x64 wave tiles.
__global__ __launch_bounds__(256, 1) void k_gemm32(
    const unsigned short* __restrict__ A, int lda,
    const unsigned short* __restrict__ Bt, int K, int Np,
    const float* __restrict__ bias, int nvalid,
    unsigned short* __restrict__ C, int ldc,
    const int* __restrict__ hdr)
{
    __shared__ unsigned short As[2][256 * 64];
    __shared__ unsigned short Bs[2][256 * 64];

    int mt = blockIdx.y;
    int e  = hdr[32 + mt * 2];
    if (e < 0) return;
    int row0 = mt * 256;
    int n0   = blockIdx.x * 256;

    int tid  = threadIdx.x;
    int wid  = tid >> 6, lane = tid & 63;
    int l31  = lane & 31, khi = lane >> 5;   // A/B operand: row/col = l31, k-half = khi
    int sw   = l31 & 7;
    int wm = (wid >> 1) * 128, wn = (wid & 1) * 128;

    const unsigned short* Ag = A  + (size_t)row0 * lda;
    const unsigned short* Bg = Bt + (size_t)e * Np * K + (size_t)n0 * K;
    const float* be = bias + (size_t)e * nvalid;

    int srow = lane >> 3;
    int scol = ((lane & 7) ^ srow) * 8;

    f32x16 acc[4][4];
#pragma unroll
    for (int i = 0; i < 4; ++i)
#pragma unroll
        for (int j = 0; j < 4; ++j)
#pragma unroll
            for (int v = 0; v < 16; ++v)
                acc[i][j][v] = 0.f;

#define STAGE(K0, P)                                                              \
    {                                                                             \
        _Pragma("unroll")                                                         \
        for (int ii = 0; ii < 8; ++ii) {                                          \
            int rbase = wid * 64 + ii * 8;                                        \
            const unsigned short* gpA = Ag + (size_t)(rbase + srow) * lda + (K0) + scol; \
            __builtin_amdgcn_global_load_lds(                                     \
                (const __attribute__((address_space(1))) void*)gpA,               \
                (__attribute__((address_space(3))) void*)(As[P] + rbase * 64), 16, 0, 0); \
            const unsigned short* gpB = Bg + (size_t)(rbase + srow) * K + (K0) + scol;   \
            __builtin_amdgcn_global_load_lds(                                     \
                (const __attribute__((address_space(1))) void*)gpB,               \
                (__attribute__((address_space(3))) void*)(Bs[P] + rbase * 64), 16, 0, 0); \
        }                                                                         \
    }

#define COMPUTE(P)                                                                \
    {                                                                             \
        _Pragma("unroll")                                                         \
        for (int ks = 0; ks < 4; ++ks) {                                          \
            int cb = ks * 2 + khi;                                                \
            bf16x8 af[4], bfr[4];                                                 \
            _Pragma("unroll")                                                     \
            for (int f = 0; f < 4; ++f) {                                         \
                int row = wm + f * 32 + l31;                                      \
                af[f] = *(const bf16x8*)(As[P] + row * 64 + ((cb ^ sw) << 3));    \
            }                                                                     \
            _Pragma("unroll")                                                     \
            for (int f = 0; f < 4; ++f) {                                         \
                int row = wn + f * 32 + l31;                                      \
                bfr[f] = *(const bf16x8*)(Bs[P] + row * 64 + ((cb ^ sw) << 3));   \
            }                                                                     \
            _Pragma("unroll")                                                     \
            for (int fm = 0; fm < 4; ++fm)                                        \
                _Pragma("unroll")                                                 \
                for (int fn = 0; fn < 4; ++fn)                                    \
                    acc[fm][fn] = __builtin_amdgcn_mfma_f32_32x32x16_bf16(        \
                        af[fm], bfr[fn], acc[fm][fn], 0, 0, 0);                   \
        }                                                                         \
    }

    STAGE(0, 0);
    __syncthreads();
    for (int k0 = 0; k0 < K; k0 += 128) {
        if (k0 + 64 < K) STAGE(k0 + 64, 1);
        COMPUTE(0);
        __syncthreads();
        if (k0 + 128 < K) STAGE(k0 + 128, 0);
        COMPUTE(1);
        __syncthreads();
    }
#undef STAGE
#undef COMPUTE

    // C/D 32x32 layout: col = lane&31, row = (i&3) + 8*(i>>2) + 4*(lane>>5)
#pragma unroll
    for (int fn = 0; fn < 4; ++fn) {
        int n = n0 + wn + fn * 32 + l31;
        float bv = be[n];
#pragma unroll
        for (int fm = 0; fm < 4; ++fm) {
#pragma unroll
            for (int i = 0; i < 16; ++i) {
                int r = row0 + wm + fm * 32 + (i & 3) + 8 * (i >> 2) + 4 * khi;
                float v = acc[fm][fn][i] + bv;
                v = v > 0.f ? v : 0.f;
                C[(size_t)r * ldc + n] = f2bf(v);
            }
        }
    }
}

__global__ void k_final(const int* hdr, float* out) {
    if (blockIdx.x == 0 && threadIdx.x == 0) {
        float s = ((const float*)hdr)[16];
        out[0] = s / (float)(B_SZ * XD);
    }
}

// ---------------- host launch ----------------
extern "C" void kernel_launch(void* const* d_in, const int* in_sizes, int n_in,
                              void* d_out, int out_size, void* d_ws, size_t ws_size,
                              hipStream_t stream) {
    const float* x     = (const float*)d_in[0];
    const float* nextv = (const float*)d_in[1];
    const int*   a     = (const int*)d_in[2];
    const float* W0 = (const float*)d_in[3],  *b0 = (const float*)d_in[4];
    const float* W1 = (const float*)d_in[5],  *b1 = (const float*)d_in[6];
    const float* W2 = (const float*)d_in[7],  *b2 = (const float*)d_in[8];
    const float* W3 = (const float*)d_in[9],  *b3 = (const float*)d_in[10];
    const float* W4 = (const float*)d_in[11], *b4 = (const float*)d_in[12];

    int* hdr    = (int*)d_ws;                 // 128 ints
    int* row_of = hdr + 128;                  // MP ints
    unsigned short* xg = (unsigned short*)(row_of + MP);     // MP*384
    unsigned short* hA = xg + (size_t)MP * 384;              // MP*2048
    unsigned short* hB = hA + (size_t)MP * 2048;             // MP*2048
    unsigned short* Wt = hB + (size_t)MP * 2048;             // 3*2048*2048
    float* accum = (float*)(hdr + 16);

    k_route <<<1, 1024, 0, stream>>>(a, hdr, row_of);
    k_gather<<<MP, 384, 0, stream>>>(x, row_of, xg);

    // L0: (Mp,384) @ (384,1024)  -- 128x128 tiles, 16x16 frags
    k_transpose<<<dim3(6, 32, 3), dim3(32, 8), 0, stream>>>(W0, Wt, XD, 1024, 384, 1024);
    k_gemm16<128, 128, 4, false><<<dim3(8, NTILES), 256, 0, stream>>>(
        xg, 384, Wt, 384, 1024, b0, 1024, hA, 1024, hdr, nullptr, nullptr, nullptr);
    // L1: (Mp,1024) @ (1024,2048) -- 256x256 blocks, 32x32 frags
    k_transpose<<<dim3(16, 64, 3), dim3(32, 8), 0, stream>>>(W1, Wt, 1024, 2048, 1024, 2048);
    k_gemm32<<<dim3(8, NTILES / 2), 256, 0, stream>>>(
        hA, 1024, Wt, 1024, 2048, b1, 2048, hB, 2048, hdr);
    // L2: (Mp,2048) @ (2048,2048)
    k_transpose<<<dim3(32, 64, 3), dim3(32, 8), 0, stream>>>(W2, Wt, 2048, 2048, 2048, 2048);
    k_gemm32<<<dim3(8, NTILES / 2), 256, 0, stream>>>(
        hB, 2048, Wt, 2048, 2048, b2, 2048, hA, 2048, hdr);
    // L3: (Mp,2048) @ (2048,1024)
    k_transpose<<<dim3(32, 32, 3), dim3(32, 8), 0, stream>>>(W3, Wt, 2048, 1024, 2048, 1024);
    k_gemm32<<<dim3(4, NTILES / 2), 256, 0, stream>>>(
        hA, 2048, Wt, 2048, 1024, b3, 1024, hB, 1024, hdr);
    // L4: (Mp,1024) @ (1024,362->384), fused MSE -- 128x128 tiles, 16x16 frags
    k_transpose<<<dim3(16, 12, 3), dim3(32, 8), 0, stream>>>(W4, Wt, 1024, XD, 1024, 384);
    k_gemm16<128, 128, 4, true><<<dim3(3, NTILES), 256, 0, stream>>>(
        hB, 1024, Wt, 1024, 384, b4, XD, nullptr, 0, hdr, nextv, row_of, accum);

    k_final<<<1, 64, 0, stream>>>(hdr, (float*)d_out);
}

// Round 6
// 529.985 us; speedup vs baseline: 1.1316x; 1.1316x over previous
//
#include <hip/hip_runtime.h>
#include <hip/hip_bf16.h>

// ---------------- problem constants ----------------
#define B_SZ   8192
#define XD     362
#define NEXP   3
#define NTILES 70          // 128-row tile capacity (segments 256-aligned)
#define MP     (NTILES*128)

typedef __bf16 bf16x8 __attribute__((ext_vector_type(8)));
typedef float  f32x4  __attribute__((ext_vector_type(4)));

__device__ __forceinline__ unsigned short f2bf(float f) {
    unsigned u = __float_as_uint(f);
    u += 0x7fffu + ((u >> 16) & 1u);
    return (unsigned short)(u >> 16);
}

// hdr: [0..2]=counts, [6..8]=seg_start_row, [12]=total 128-tiles,
// [13]=last 256-tile index (nt/2-1), [16]=float accumulator,
// [32..101]=128-tile -> expert (-1 = inactive)
__global__ __launch_bounds__(1024) void k_route(const int* __restrict__ a,
                                                int* __restrict__ hdr,
                                                int* __restrict__ row_of) {
    __shared__ int sc[3][1024];
    int tid = threadIdx.x;
    int ev[8];
    int c0 = 0, c1 = 0, c2 = 0;
#pragma unroll
    for (int j = 0; j < 8; ++j) {
        int e = a[tid * 8 + j];
        ev[j] = e;
        c0 += (e == 0); c1 += (e == 1); c2 += (e == 2);
    }
    sc[0][tid] = c0; sc[1][tid] = c1; sc[2][tid] = c2;
    __syncthreads();
    for (int off = 1; off < 1024; off <<= 1) {
        int v0 = (tid >= off) ? sc[0][tid - off] : 0;
        int v1 = (tid >= off) ? sc[1][tid - off] : 0;
        int v2 = (tid >= off) ? sc[2][tid - off] : 0;
        __syncthreads();
        sc[0][tid] += v0; sc[1][tid] += v1; sc[2][tid] += v2;
        __syncthreads();
    }
    int tot0 = sc[0][1023], tot1 = sc[1][1023], tot2 = sc[2][1023];
    int t0 = ((tot0 + 255) >> 8) << 1;   // 128-tiles per expert, 256-aligned
    int t1 = ((tot1 + 255) >> 8) << 1;
    int t2 = ((tot2 + 255) >> 8) << 1;
    int seg0 = 0, seg1 = t0 * 128, seg2 = (t0 + t1) * 128;
    int nt = t0 + t1 + t2;
    int b0 = seg0 + sc[0][tid] - c0;
    int b1 = seg1 + sc[1][tid] - c1;
    int b2 = seg2 + sc[2][tid] - c2;
#pragma unroll
    for (int j = 0; j < 8; ++j) {
        int e = ev[j];
        int pos = (e == 0) ? b0++ : (e == 1) ? b1++ : b2++;
        row_of[pos] = tid * 8 + j;
    }
    if (tid == 0) {
        hdr[0] = tot0; hdr[1] = tot1; hdr[2] = tot2;
        hdr[6] = seg0; hdr[7] = seg1; hdr[8] = seg2;
        hdr[12] = nt;
        hdr[13] = nt / 2 - 1;     // last 256-row tile index
        hdr[16] = 0;
    }
    if (tid < NTILES)
        hdr[32 + tid] = (tid < t0) ? 0 : (tid < t0 + t1) ? 1 : (tid < nt) ? 2 : -1;
    for (int r = tid; r < MP; r += 1024) {
        int pad;
        if (r < seg1)           pad = (r - seg0) >= tot0;
        else if (r < seg2)      pad = (r - seg1) >= tot1;
        else if (r < nt * 128)  pad = (r - seg2) >= tot2;
        else                    pad = 1;
        if (pad) row_of[r] = -1;
    }
}

__global__ void k_gather(const float* __restrict__ x, const int* __restrict__ row_of,
                         unsigned short* __restrict__ xg) {
    int r = blockIdx.x;
    int c = threadIdx.x;
    int orig = row_of[r];
    float v = (orig >= 0 && c < XD) ? x[(size_t)orig * XD + c] : 0.f;
    xg[(size_t)r * 384 + c] = f2bf(v);
}

// ---------------- weight transpose+convert: W[e](K,N) f32 -> Wt[e](Np,Kp) bf16 ----------------
__global__ void k_transpose(const float* __restrict__ W, unsigned short* __restrict__ Wt,
                            int K, int N, int Kp, int Np) {
    __shared__ float t[64][33];
    int e  = blockIdx.z;
    int kb = blockIdx.x * 64, nb = blockIdx.y * 32;
    const float* We = W + (size_t)e * K * N;
    unsigned short* Wte = Wt + (size_t)e * Np * Kp;
    int tx = threadIdx.x, ty = threadIdx.y;
#pragma unroll
    for (int j = 0; j < 8; ++j) {
        int k = kb + ty + j * 8, n = nb + tx;
        t[ty + j * 8][tx] = (k < K && n < N) ? We[(size_t)k * N + n] : 0.f;
    }
    __syncthreads();
#pragma unroll
    for (int j = 0; j < 4; ++j) {
        int n = ty + j * 8;
        unsigned int lo = f2bf(t[2 * tx][n]);
        unsigned int hi = f2bf(t[2 * tx + 1][n]);
        *(unsigned int*)&Wte[(size_t)(nb + n) * Kp + kb + 2 * tx] = lo | (hi << 16);
    }
}

// ---------------- GEMM: C[M,N] = A[M,K] @ Wt^T, routed m-tiles ----------------
// TM x TN tile, BK=64, WAVES waves each a 64x64 sub-tile (4x4 frags of 16x16x32).
// Single-barrier double-buffered pipeline. LDS XOR-swizzle (c ^ (r&7)). K%128==0.
// SKIPLAST: skip the final 256-row m-tile (handled by a TAIL launch of 128x128 blocks
// so the grid's full-block count lands on exactly (nt256-1)*nstrips = ~256 blocks).
template <int TM, int TN, int WAVES, bool FINAL, bool TAIL, bool SKIPLAST>
__global__ __launch_bounds__(WAVES * 64) void k_gemm(
    const unsigned short* __restrict__ A, int lda,
    const unsigned short* __restrict__ Bt, int K, int Np,
    const float* __restrict__ bias, int nvalid,
    unsigned short* __restrict__ C, int ldc,
    const int* __restrict__ hdr,
    const float* __restrict__ nextv, const int* __restrict__ row_of,
    float* __restrict__ accum)
{
    __shared__ unsigned short As[2][TM * 64];
    __shared__ unsigned short Bs[2][TN * 64];
    __shared__ float red[WAVES];

    constexpr int WGN = TN / 64;
    constexpr int LA  = TM / (WAVES * 8);
    constexpr int LB  = TN / (WAVES * 8);

    int mt128;
    if constexpr (TAIL) {
        mt128 = hdr[13] * 2 + blockIdx.y;    // the two 128-halves of the last 256-tile
    } else {
        if (SKIPLAST && (int)blockIdx.y >= hdr[13] && TM == 256) return;
        mt128 = blockIdx.y * (TM / 128);
    }
    int e = hdr[32 + mt128];
    if (e < 0) return;
    int row0 = mt128 * 128;
    int n0   = blockIdx.x * TN;

    int tid  = threadIdx.x;
    int wid  = tid >> 6, lane = tid & 63;
    int quad = lane >> 4, l15 = lane & 15;
    int sw   = l15 & 7;
    int wm = (wid / WGN) * 64, wn = (wid % WGN) * 64;

    const unsigned short* Ag = A  + (size_t)row0 * lda;
    const unsigned short* Bg = Bt + (size_t)e * Np * K + (size_t)n0 * K;
    const float* be = bias + (size_t)e * nvalid;

    int srow = lane >> 3;
    int scol = ((lane & 7) ^ srow) * 8;

    f32x4 acc[4][4];
#pragma unroll
    for (int i = 0; i < 4; ++i)
#pragma unroll
        for (int j = 0; j < 4; ++j)
            acc[i][j] = (f32x4){0.f, 0.f, 0.f, 0.f};

#define STAGE(K0, P)                                                              \
    {                                                                             \
        _Pragma("unroll")                                                         \
        for (int ii = 0; ii < LA; ++ii) {                                         \
            int rbase = wid * (TM / WAVES) + ii * 8;                              \
            const unsigned short* gp = Ag + (size_t)(rbase + srow) * lda + (K0) + scol; \
            __builtin_amdgcn_global_load_lds(                                     \
                (const __attribute__((address_space(1))) void*)gp,                \
                (__attribute__((address_space(3))) void*)(As[P] + rbase * 64), 16, 0, 0); \
        }                                                                         \
        _Pragma("unroll")                                                         \
        for (int ii = 0; ii < LB; ++ii) {                                         \
            int rbase = wid * (TN / WAVES) + ii * 8;                              \
            const unsigned short* gp = Bg + (size_t)(rbase + srow) * K + (K0) + scol;   \
            __builtin_amdgcn_global_load_lds(                                     \
                (const __attribute__((address_space(1))) void*)gp,                \
                (__attribute__((address_space(3))) void*)(Bs[P] + rbase * 64), 16, 0, 0); \
        }                                                                         \
    }

#define COMPUTE(P)                                                                \
    {                                                                             \
        _Pragma("unroll")                                                         \
        for (int kh = 0; kh < 2; ++kh) {                                          \
            bf16x8 af[4], bfr[4];                                                 \
            _Pragma("unroll")                                                     \
            for (int f = 0; f < 4; ++f) {                                         \
                int row = wm + f * 16 + l15;                                      \
                af[f] = *(const bf16x8*)(As[P] + row * 64 + (((kh * 4 + quad) ^ sw) << 3)); \
            }                                                                     \
            _Pragma("unroll")                                                     \
            for (int f = 0; f < 4; ++f) {                                         \
                int row = wn + f * 16 + l15;                                      \
                bfr[f] = *(const bf16x8*)(Bs[P] + row * 64 + (((kh * 4 + quad) ^ sw) << 3)); \
            }                                                                     \
            _Pragma("unroll")                                                     \
            for (int fm = 0; fm < 4; ++fm)                                        \
                _Pragma("unroll")                                                 \
                for (int fn = 0; fn < 4; ++fn)                                    \
                    acc[fm][fn] = __builtin_amdgcn_mfma_f32_16x16x32_bf16(        \
                        af[fm], bfr[fn], acc[fm][fn], 0, 0, 0);                   \
        }                                                                         \
    }

    STAGE(0, 0);
    __syncthreads();
    for (int k0 = 0; k0 < K; k0 += 128) {
        if (k0 + 64 < K) STAGE(k0 + 64, 1);
        COMPUTE(0);
        __syncthreads();
        if (k0 + 128 < K) STAGE(k0 + 128, 0);
        COMPUTE(1);
        __syncthreads();
    }
#undef STAGE
#undef COMPUTE

    if constexpr (!FINAL) {
#pragma unroll
        for (int fn = 0; fn < 4; ++fn) {
            int n = n0 + wn + fn * 16 + l15;
            float bv = be[n];
#pragma unroll
            for (int fm = 0; fm < 4; ++fm) {
#pragma unroll
                for (int i = 0; i < 4; ++i) {
                    int r = row0 + wm + fm * 16 + quad * 4 + i;
                    float v = acc[fm][fn][i] + bv;
                    v = v > 0.f ? v : 0.f;
                    C[(size_t)r * ldc + n] = f2bf(v);
                }
            }
        }
    } else {
        float local = 0.f;
#pragma unroll
        for (int fm = 0; fm < 4; ++fm) {
#pragma unroll
            for (int i = 0; i < 4; ++i) {
                int r = row0 + wm + fm * 16 + quad * 4 + i;
                int orig = row_of[r];
                if (orig >= 0) {
                    const float* nrow = nextv + (size_t)orig * XD;
#pragma unroll
                    for (int fn = 0; fn < 4; ++fn) {
                        int n = n0 + wn + fn * 16 + l15;
                        if (n < XD) {
                            float v = acc[fm][fn][i] + be[n];
                            float d = v - nrow[n];
                            local += d * d;
                        }
                    }
                }
            }
        }
        for (int off = 32; off > 0; off >>= 1)
            local += __shfl_down(local, off, 64);
        if (lane == 0) red[wid] = local;
        __syncthreads();
        if (tid == 0) {
            float s = 0.f;
#pragma unroll
            for (int w = 0; w < WAVES; ++w) s += red[w];
            atomicAdd(accum, s);
        }
    }
}

__global__ void k_final(const int* hdr, float* out) {
    if (blockIdx.x == 0 && threadIdx.x == 0) {
        float s = ((const float*)hdr)[16];
        out[0] = s / (float)(B_SZ * XD);
    }
}

// ---------------- host launch ----------------
extern "C" void kernel_launch(void* const* d_in, const int* in_sizes, int n_in,
                              void* d_out, int out_size, void* d_ws, size_t ws_size,
                              hipStream_t stream) {
    const float* x     = (const float*)d_in[0];
    const float* nextv = (const float*)d_in[1];
    const int*   a     = (const int*)d_in[2];
    const float* W0 = (const float*)d_in[3],  *b0 = (const float*)d_in[4];
    const float* W1 = (const float*)d_in[5],  *b1 = (const float*)d_in[6];
    const float* W2 = (const float*)d_in[7],  *b2 = (const float*)d_in[8];
    const float* W3 = (const float*)d_in[9],  *b3 = (const float*)d_in[10];
    const float* W4 = (const float*)d_in[11], *b4 = (const float*)d_in[12];

    int* hdr    = (int*)d_ws;                 // 128 ints
    int* row_of = hdr + 128;                  // MP ints
    unsigned short* xg = (unsigned short*)(row_of + MP);     // MP*384
    unsigned short* hA = xg + (size_t)MP * 384;              // MP*2048
    unsigned short* hB = hA + (size_t)MP * 2048;             // MP*2048
    unsigned short* Wt = hB + (size_t)MP * 2048;             // 3*2048*2048
    float* accum = (float*)(hdr + 16);

    k_route <<<1, 1024, 0, stream>>>(a, hdr, row_of);
    k_gather<<<MP, 384, 0, stream>>>(x, row_of, xg);

    // L0: (Mp,384) @ (384,1024)  -- 128x128 tiles (small K; fine-grained grid)
    k_transpose<<<dim3(6, 32, 3), dim3(32, 8), 0, stream>>>(W0, Wt, XD, 1024, 384, 1024);
    k_gemm<128, 128, 4, false, false, false><<<dim3(8, NTILES), 256, 0, stream>>>(
        xg, 384, Wt, 384, 1024, b0, 1024, hA, 1024, hdr, nullptr, nullptr, nullptr);

    // L1: (Mp,1024) @ (1024,2048) -- main 256x256 (typ. exactly 256 blocks) + 128x128 tail
    k_transpose<<<dim3(16, 64, 3), dim3(32, 8), 0, stream>>>(W1, Wt, 1024, 2048, 1024, 2048);
    k_gemm<256, 256, 16, false, false, true><<<dim3(8, NTILES / 2), 1024, 0, stream>>>(
        hA, 1024, Wt, 1024, 2048, b1, 2048, hB, 2048, hdr, nullptr, nullptr, nullptr);
    k_gemm<128, 128, 4, false, true, false><<<dim3(16, 2), 256, 0, stream>>>(
        hA, 1024, Wt, 1024, 2048, b1, 2048, hB, 2048, hdr, nullptr, nullptr, nullptr);

    // L2: (Mp,2048) @ (2048,2048)
    k_transpose<<<dim3(32, 64, 3), dim3(32, 8), 0, stream>>>(W2, Wt, 2048, 2048, 2048, 2048);
    k_gemm<256, 256, 16, false, false, true><<<dim3(8, NTILES / 2), 1024, 0, stream>>>(
        hB, 2048, Wt, 2048, 2048, b2, 2048, hA, 2048, hdr, nullptr, nullptr, nullptr);
    k_gemm<128, 128, 4, false, true, false><<<dim3(16, 2), 256, 0, stream>>>(
        hB, 2048, Wt, 2048, 2048, b2, 2048, hA, 2048, hdr, nullptr, nullptr, nullptr);

    // L3: (Mp,2048) @ (2048,1024)
    k_transpose<<<dim3(32, 32, 3), dim3(32, 8), 0, stream>>>(W3, Wt, 2048, 1024, 2048, 1024);
    k_gemm<256, 256, 16, false, false, true><<<dim3(4, NTILES / 2), 1024, 0, stream>>>(
        hA, 2048, Wt, 2048, 1024, b3, 1024, hB, 1024, hdr, nullptr, nullptr, nullptr);
    k_gemm<128, 128, 4, false, true, false><<<dim3(8, 2), 256, 0, stream>>>(
        hA, 2048, Wt, 2048, 1024, b3, 1024, hB, 1024, hdr, nullptr, nullptr, nullptr);

    // L4: (Mp,1024) @ (1024,362->384), fused MSE -- all 128-tiles
    k_transpose<<<dim3(16, 12, 3), dim3(32, 8), 0, stream>>>(W4, Wt, 1024, XD, 1024, 384);
    k_gemm<128, 128, 4, true, false, false><<<dim3(3, NTILES), 256, 0, stream>>>(
        hB, 1024, Wt, 1024, 384, b4, XD, nullptr, 0, hdr, nextv, row_of, accum);

    k_final<<<1, 64, 0, stream>>>(hdr, (float*)d_out);
}